// Round 1
// baseline (264.717 us; speedup 1.0000x reference)
//
#include <hip/hip_runtime.h>

#define DEVI __device__ __forceinline__

typedef unsigned short u16;
typedef unsigned int u32;
typedef __attribute__((ext_vector_type(8))) __bf16 bf16x8;
typedef __attribute__((ext_vector_type(4))) float f32x4;

DEVI u16 f2bf(float f){
  u32 u = __float_as_uint(f);
  return (u16)((u + 0x7FFFu + ((u >> 16) & 1u)) >> 16);
}

// ---------------- GroupNorm: x[b,c,l] fp32 -> nx[b,c,l] bf16 ----------------
__global__ __launch_bounds__(256) void gn_kernel(const float* __restrict__ x,
                                                 const float* __restrict__ gw,
                                                 const float* __restrict__ gb,
                                                 u16* __restrict__ nx){
  int b = blockIdx.x >> 5, g = blockIdx.x & 31;
  size_t base = ((size_t)(b * 512 + g * 16)) * 2048;   // group block = 32768 contiguous floats
  const float4* xin = (const float4*)(x + base);
  int tid = threadIdx.x;
  float s1 = 0.f, s2 = 0.f;
  for (int i = tid; i < 8192; i += 256){
    float4 v = xin[i];
    s1 += v.x + v.y + v.z + v.w;
    s2 += v.x*v.x + v.y*v.y + v.z*v.z + v.w*v.w;
  }
  __shared__ float red[8];
  int lane = tid & 63, w = tid >> 6;
  for (int off = 32; off; off >>= 1){
    s1 += __shfl_down(s1, off);
    s2 += __shfl_down(s2, off);
  }
  if (lane == 0){ red[w] = s1; red[4 + w] = s2; }
  __syncthreads();
  if (tid == 0){
    float a = red[0]+red[1]+red[2]+red[3];
    float c = red[4]+red[5]+red[6]+red[7];
    float mu = a * (1.f/32768.f);
    float var = c * (1.f/32768.f) - mu*mu;
    red[0] = mu; red[1] = rsqrtf(var + 1e-5f);
  }
  __syncthreads();
  float mu = red[0], rs = red[1];
  ushort4* outp = (ushort4*)(nx + base);
  for (int i = tid; i < 8192; i += 256){
    float4 v = xin[i];
    int ch = g*16 + (i >> 9);             // i in float4 units; /512 -> channel within group
    float ga = gw[ch] * rs;
    float be = gb[ch] - mu * ga;
    ushort4 o;
    o.x = f2bf(v.x*ga + be); o.y = f2bf(v.y*ga + be);
    o.z = f2bf(v.z*ga + be); o.w = f2bf(v.w*ga + be);
    outp[i] = o;
  }
}

// ---------------- cast weights fp32 -> bf16 ----------------
__global__ __launch_bounds__(256) void castw_kernel(const float* __restrict__ wq,
                                                    const float* __restrict__ wo,
                                                    u16* __restrict__ wqb,
                                                    u16* __restrict__ wob){
  int t = blockIdx.x * 256 + threadIdx.x;     // 262144 float4 tasks
  const int NQ4 = (1536*512)/4;               // 196608
  float4 v; u16* dst;
  if (t < NQ4){ v = ((const float4*)wq)[t]; dst = wqb + t*4; }
  else        { int u_ = t - NQ4; v = ((const float4*)wo)[u_]; dst = wob + u_*4; }
  ushort4 s;
  s.x = f2bf(v.x); s.y = f2bf(v.y); s.z = f2bf(v.z); s.w = f2bf(v.w);
  *(ushort4*)dst = s;
}

// ---------------- transpose nx[b][c][l] -> nxT[b][l][c] (bf16) ----------------
__global__ __launch_bounds__(256) void transpose_kernel(const u16* __restrict__ nx,
                                                        u16* __restrict__ nxT){
  int b = blockIdx.z, c0 = blockIdx.y * 64, l0 = blockIdx.x * 64;
  __shared__ u16 T[64][72];
  int tid = threadIdx.x;
  for (int rep = 0; rep < 2; ++rep){
    int task = tid + rep*256;
    int r = task >> 3, cc = task & 7;
    *(uint4*)&T[r][cc*8] =
      *(const uint4*)(nx + ((size_t)(b*512 + c0 + r))*2048 + l0 + cc*8);
  }
  __syncthreads();
  for (int rep = 0; rep < 2; ++rep){
    int task = tid + rep*256;
    int r = task >> 3, cc = task & 7;   // r = local l, cc = c-chunk
    u16 tmp[8];
    #pragma unroll
    for (int i = 0; i < 8; ++i) tmp[i] = T[cc*8 + i][r];
    *(uint4*)(nxT + ((size_t)(b*2048 + l0 + r))*512 + c0 + cc*8) = *(uint4*)tmp;
  }
}

// ---------------- GEMM: C[o][l] = sum_c A[o][c] * B[l][c]^T  (bf16 MFMA) ----
// A: [M][512] row-major bf16. Bm: [b][2048][512] row-major bf16.
// MODE 0: epilogue splits into qT/kT ([b][h][l][d], q*0.125) and v ([b][h][d][l]).
// MODE 1: epilogue adds b_out[o] + x residual, writes fp32 d_out[b][o][l].
template<int MODE>
__global__ __launch_bounds__(256) void gemm_kernel(const u16* __restrict__ A,
                                                   const u16* __restrict__ Bm,
                                                   u16* __restrict__ q_o,
                                                   u16* __restrict__ k_o,
                                                   u16* __restrict__ v_o,
                                                   const float* __restrict__ bo,
                                                   const float* __restrict__ xres,
                                                   float* __restrict__ out){
  int b  = blockIdx.z;
  int n0 = blockIdx.x * 128, m0 = blockIdx.y * 128;
  int tid = threadIdx.x, w = tid >> 6, lane = tid & 63, lq = lane >> 4, lr = lane & 15;
  int wm = (w >> 1) * 64, wn = (w & 1) * 64;
  __shared__ u16 Al[128][40], Bl[128][40];
  f32x4 acc[4][4] = {};
  const u16* Bb = Bm + (size_t)b * 2048 * 512;

  for (int k0 = 0; k0 < 512; k0 += 32){
    #pragma unroll
    for (int rep = 0; rep < 2; ++rep){
      int task = tid + rep*256;
      int row = task >> 2, kc = task & 3;
      *(uint4*)&Al[row][kc*8] = *(const uint4*)(A  + (size_t)(m0+row)*512 + k0 + kc*8);
      *(uint4*)&Bl[row][kc*8] = *(const uint4*)(Bb + (size_t)(n0+row)*512 + k0 + kc*8);
    }
    __syncthreads();
    bf16x8 af[4], bfr[4];
    #pragma unroll
    for (int i = 0; i < 4; ++i) af[i]  = *(const bf16x8*)&Al[wm + i*16 + lr][lq*8];
    #pragma unroll
    for (int j = 0; j < 4; ++j) bfr[j] = *(const bf16x8*)&Bl[wn + j*16 + lr][lq*8];
    #pragma unroll
    for (int i = 0; i < 4; ++i)
      #pragma unroll
      for (int j = 0; j < 4; ++j)
        acc[i][j] = __builtin_amdgcn_mfma_f32_16x16x32_bf16(af[i], bfr[j], acc[i][j], 0, 0, 0);
    __syncthreads();
  }

  if (MODE == 0){
    #pragma unroll
    for (int i = 0; i < 4; ++i){
      int o0  = m0 + wm + i*16 + lq*4;          // 4 consecutive o, aligned
      int cls = o0 >> 9;                        // 0=q 1=k 2=v
      int hh  = (o0 >> 6) & 7;
      int d0  = o0 & 63;
      #pragma unroll
      for (int j = 0; j < 4; ++j){
        int l = n0 + wn + j*16 + lr;
        f32x4 v = acc[i][j];
        if (cls == 0){
          ushort4 s;
          s.x = f2bf(v[0]*0.125f); s.y = f2bf(v[1]*0.125f);
          s.z = f2bf(v[2]*0.125f); s.w = f2bf(v[3]*0.125f);
          *(ushort4*)(q_o + (((size_t)(b*8+hh))*2048 + l)*64 + d0) = s;
        } else if (cls == 1){
          ushort4 s;
          s.x = f2bf(v[0]); s.y = f2bf(v[1]); s.z = f2bf(v[2]); s.w = f2bf(v[3]);
          *(ushort4*)(k_o + (((size_t)(b*8+hh))*2048 + l)*64 + d0) = s;
        } else {
          #pragma unroll
          for (int r = 0; r < 4; ++r)
            v_o[(((size_t)(b*8+hh))*64 + d0 + r)*2048 + l] = f2bf(v[r]);
        }
      }
    }
  } else {
    #pragma unroll
    for (int i = 0; i < 4; ++i){
      int o0 = m0 + wm + i*16 + lq*4;
      #pragma unroll
      for (int j = 0; j < 4; ++j){
        int l = n0 + wn + j*16 + lr;
        #pragma unroll
        for (int r = 0; r < 4; ++r){
          int o = o0 + r;
          size_t idx = ((size_t)b*512 + o)*2048 + l;
          out[idx] = acc[i][j][r] + bo[o] + xres[idx];
        }
      }
    }
  }
}

// ---------------- flash attention ----------------
// qT,kT: [b][h][l][64] bf16 (q pre-scaled). vv: [b][h][64][l] bf16.
// ao out: [b][l][h*64+d] bf16.
__global__ __launch_bounds__(256) void attn_kernel(const u16* __restrict__ qT,
                                                   const u16* __restrict__ kT,
                                                   const u16* __restrict__ vv,
                                                   u16* __restrict__ ao){
  int qb = blockIdx.x, h = blockIdx.y, b = blockIdx.z;
  int tid = threadIdx.x, w = tid >> 6, lane = tid & 63, lq = lane >> 4, lr = lane & 15;
  int i0 = qb*64 + w*16;
  size_t headoff = ((size_t)(b*8 + h)) * 2048 * 64;
  __shared__ u16 Kl[64][72], Vl[64][72], Pl[4][16][72];

  bf16x8 qf0 = *(const bf16x8*)(qT + headoff + (size_t)(i0 + lr)*64 + lq*8);
  bf16x8 qf1 = *(const bf16x8*)(qT + headoff + (size_t)(i0 + lr)*64 + 32 + lq*8);

  f32x4 of[4] = {};
  float mrow[4] = {-1e30f, -1e30f, -1e30f, -1e30f};
  float lrow[4] = {0.f, 0.f, 0.f, 0.f};

  for (int j0 = 0; j0 < 2048; j0 += 64){
    #pragma unroll
    for (int rep = 0; rep < 2; ++rep){
      int task = tid + rep*256;
      int r = task >> 3, cc = task & 7;
      *(uint4*)&Kl[r][cc*8] = *(const uint4*)(kT + headoff + (size_t)(j0 + r)*64 + cc*8);
      *(uint4*)&Vl[r][cc*8] = *(const uint4*)(vv + headoff + (size_t)r*2048 + j0 + cc*8);
    }
    __syncthreads();

    f32x4 sa[4] = {};
    #pragma unroll
    for (int jt = 0; jt < 4; ++jt){
      bf16x8 kf0 = *(const bf16x8*)&Kl[jt*16 + lr][lq*8];
      bf16x8 kf1 = *(const bf16x8*)&Kl[jt*16 + lr][32 + lq*8];
      sa[jt] = __builtin_amdgcn_mfma_f32_16x16x32_bf16(qf0, kf0, sa[jt], 0, 0, 0);
      sa[jt] = __builtin_amdgcn_mfma_f32_16x16x32_bf16(qf1, kf1, sa[jt], 0, 0, 0);
    }

    float alpha[4];
    #pragma unroll
    for (int r = 0; r < 4; ++r){
      float cm = fmaxf(fmaxf(sa[0][r], sa[1][r]), fmaxf(sa[2][r], sa[3][r]));
      #pragma unroll
      for (int off = 1; off < 16; off <<= 1) cm = fmaxf(cm, __shfl_xor(cm, off));
      float nm = fmaxf(mrow[r], cm);
      alpha[r] = __expf(mrow[r] - nm);
      mrow[r] = nm;
      float rs = 0.f;
      #pragma unroll
      for (int jt = 0; jt < 4; ++jt){
        float p = __expf(sa[jt][r] - nm);
        sa[jt][r] = p; rs += p;
      }
      #pragma unroll
      for (int off = 1; off < 16; off <<= 1) rs += __shfl_xor(rs, off);
      lrow[r] = lrow[r]*alpha[r] + rs;
    }
    #pragma unroll
    for (int dt = 0; dt < 4; ++dt){
      f32x4 t = of[dt];
      t[0] *= alpha[0]; t[1] *= alpha[1]; t[2] *= alpha[2]; t[3] *= alpha[3];
      of[dt] = t;
    }
    // P -> per-wave LDS (A-operand layout round trip)
    #pragma unroll
    for (int jt = 0; jt < 4; ++jt)
      #pragma unroll
      for (int r = 0; r < 4; ++r)
        Pl[w][lq*4 + r][jt*16 + lr] = f2bf(sa[jt][r]);

    #pragma unroll
    for (int jk = 0; jk < 2; ++jk){
      bf16x8 pa = *(const bf16x8*)&Pl[w][lr][jk*32 + lq*8];
      #pragma unroll
      for (int dt = 0; dt < 4; ++dt){
        bf16x8 vb = *(const bf16x8*)&Vl[dt*16 + lr][jk*32 + lq*8];
        of[dt] = __builtin_amdgcn_mfma_f32_16x16x32_bf16(pa, vb, of[dt], 0, 0, 0);
      }
    }
    __syncthreads();
  }

  float inv[4];
  #pragma unroll
  for (int r = 0; r < 4; ++r) inv[r] = 1.f / lrow[r];
  #pragma unroll
  for (int dt = 0; dt < 4; ++dt)
    #pragma unroll
    for (int r = 0; r < 4; ++r)
      ao[((size_t)(b*2048) + i0 + lq*4 + r)*512 + h*64 + dt*16 + lr] = f2bf(of[dt][r]*inv[r]);
}

extern "C" void kernel_launch(void* const* d_in, const int* in_sizes, int n_in,
                              void* d_out, int out_size, void* d_ws, size_t ws_size,
                              hipStream_t stream) {
  const float* x    = (const float*)d_in[0];
  const float* gw   = (const float*)d_in[1];
  const float* gb   = (const float*)d_in[2];
  const float* wqkv = (const float*)d_in[3];
  const float* wout = (const float*)d_in[4];
  const float* bout = (const float*)d_in[5];
  float* out = (float*)d_out;
  char* ws = (char*)d_ws;

  // workspace layout (bytes)
  const size_t SZ_NX = (size_t)4*512*2048*2;        // 8,388,608
  u16* nx  = (u16*)(ws);
  u16* nxT = (u16*)(ws + SZ_NX);
  u16* wqb = (u16*)(ws + 2*SZ_NX);                  // 1,572,864
  u16* wob = (u16*)(ws + 2*SZ_NX + 1572864);        // 524,288
  u16* qT  = (u16*)(ws + 2*SZ_NX + 2097152);
  u16* kT  = qT + (size_t)4*8*2048*64;
  u16* vv  = kT + (size_t)4*8*2048*64;
  u16* ao  = nx;                                    // alias: nx dead after transpose+QKV

  gn_kernel<<<128, 256, 0, stream>>>(x, gw, gb, nx);
  castw_kernel<<<1024, 256, 0, stream>>>(wqkv, wout, wqb, wob);
  transpose_kernel<<<dim3(32, 8, 4), 256, 0, stream>>>(nx, nxT);
  gemm_kernel<0><<<dim3(16, 12, 4), 256, 0, stream>>>(wqb, nxT, qT, kT, vv,
                                                      nullptr, nullptr, nullptr);
  attn_kernel<<<dim3(32, 8, 4), 256, 0, stream>>>(qT, kT, vv, ao);
  gemm_kernel<1><<<dim3(16, 4, 4), 256, 0, stream>>>(wob, ao, nullptr, nullptr, nullptr,
                                                     bout, x, out);
}

// Round 4
// 204.589 us; speedup vs baseline: 1.2939x; 1.2939x over previous
//
#include <hip/hip_runtime.h>

#define DEVI __device__ __forceinline__

typedef unsigned short u16;
typedef unsigned int u32;
typedef __attribute__((ext_vector_type(8))) __bf16 bf16x8;
typedef __attribute__((ext_vector_type(4))) __bf16 bf16x4;
typedef __attribute__((ext_vector_type(4))) float f32x4;

DEVI u16 f2bf(float f){
  u32 u = __float_as_uint(f);
  return (u16)((u + 0x7FFFu + ((u >> 16) & 1u)) >> 16);
}

// ---------------- GN pass 1: partial sums per (group, quarter) ----------------
__global__ __launch_bounds__(256) void gnstat_kernel(const float* __restrict__ x,
                                                     float2* __restrict__ pstat){
  int bg = blockIdx.x >> 2, qt = blockIdx.x & 3;
  const float4* xin = (const float4*)(x + (size_t)bg*32768 + qt*8192);
  int tid = threadIdx.x;
  float s1 = 0.f, s2 = 0.f;
  #pragma unroll
  for (int i = 0; i < 8; ++i){
    float4 v = xin[tid + i*256];
    s1 += v.x + v.y + v.z + v.w;
    s2 += v.x*v.x + v.y*v.y + v.z*v.z + v.w*v.w;
  }
  __shared__ float red[8];
  int lane = tid & 63, w = tid >> 6;
  for (int off = 32; off; off >>= 1){
    s1 += __shfl_down(s1, off);
    s2 += __shfl_down(s2, off);
  }
  if (lane == 0){ red[w] = s1; red[4 + w] = s2; }
  __syncthreads();
  if (tid == 0){
    pstat[blockIdx.x] = make_float2(red[0]+red[1]+red[2]+red[3],
                                    red[4]+red[5]+red[6]+red[7]);
  }
}

// ---------------- GN pass 2: finalize mu/rsigma per group ----------------
__global__ __launch_bounds__(128) void gnfin_kernel(const float2* __restrict__ pstat,
                                                    float2* __restrict__ stat){
  int t = threadIdx.x;       // 128 groups total (4 b * 32 g)
  float s1 = 0.f, s2 = 0.f;
  #pragma unroll
  for (int i = 0; i < 4; ++i){
    float2 p = pstat[t*4 + i];
    s1 += p.x; s2 += p.y;
  }
  float mu = s1 * (1.f/32768.f);
  float var = s2 * (1.f/32768.f) - mu*mu;
  stat[t] = make_float2(mu, rsqrtf(var + 1e-5f));
}

// ------- normalize + transpose: x[b][c][l] fp32 -> nxT[b][l][c] bf16 -------
__global__ __launch_bounds__(256) void normtrans_kernel(const float* __restrict__ x,
                                                        const float2* __restrict__ stat,
                                                        const float* __restrict__ gw,
                                                        const float* __restrict__ gb,
                                                        u16* __restrict__ nxT){
  int b = blockIdx.z, c0 = blockIdx.y * 64, l0 = blockIdx.x * 64;
  __shared__ u16 T[64][72];
  int tid = threadIdx.x;
  #pragma unroll
  for (int rep = 0; rep < 2; ++rep){
    int task = tid + rep*256;
    int r = task >> 3, cc = task & 7;          // channel row r, l-chunk cc
    int ch = c0 + r;
    float2 st = stat[b*32 + (ch >> 4)];
    float ga = gw[ch] * st.y;
    float be = gb[ch] - st.x * ga;
    const float4* src = (const float4*)(x + ((size_t)(b*512 + ch))*2048 + l0 + cc*8);
    float4 v0 = src[0], v1 = src[1];
    ushort4 o0, o1;
    o0.x = f2bf(v0.x*ga + be); o0.y = f2bf(v0.y*ga + be);
    o0.z = f2bf(v0.z*ga + be); o0.w = f2bf(v0.w*ga + be);
    o1.x = f2bf(v1.x*ga + be); o1.y = f2bf(v1.y*ga + be);
    o1.z = f2bf(v1.z*ga + be); o1.w = f2bf(v1.w*ga + be);
    *(ushort4*)&T[r][cc*8]     = o0;
    *(ushort4*)&T[r][cc*8 + 4] = o1;
  }
  __syncthreads();
  #pragma unroll
  for (int rep = 0; rep < 2; ++rep){
    int task = tid + rep*256;
    int r = task >> 3, cc = task & 7;          // r = local l, cc = c-chunk
    u16 tmp[8];
    #pragma unroll
    for (int i = 0; i < 8; ++i) tmp[i] = T[cc*8 + i][r];
    *(uint4*)(nxT + ((size_t)(b*2048 + l0 + r))*512 + c0 + cc*8) = *(uint4*)tmp;
  }
}

// ---------------- cast weights fp32 -> bf16 ----------------
__global__ __launch_bounds__(256) void castw_kernel(const float* __restrict__ wq,
                                                    const float* __restrict__ wo,
                                                    u16* __restrict__ wqb,
                                                    u16* __restrict__ wob){
  int t = blockIdx.x * 256 + threadIdx.x;     // 262144 float4 tasks
  const int NQ4 = (1536*512)/4;               // 196608
  float4 v; u16* dst;
  if (t < NQ4){ v = ((const float4*)wq)[t]; dst = wqb + t*4; }
  else        { int u_ = t - NQ4; v = ((const float4*)wo)[u_]; dst = wob + u_*4; }
  ushort4 s;
  s.x = f2bf(v.x); s.y = f2bf(v.y); s.z = f2bf(v.z); s.w = f2bf(v.w);
  *(ushort4*)dst = s;
}

// ---------------- GEMM: C[o][l] = sum_c A[o][c] * B[l][c]^T  (bf16 MFMA) ----
// MODE 0: epilogue -> qT ([b][h][l][d], q*0.125*log2e), kT, v ([b][h][d][l]).
// MODE 1: epilogue adds b_out[o] + x residual, writes fp32 d_out[b][o][l].
template<int MODE>
__global__ __launch_bounds__(256) void gemm_kernel(const u16* __restrict__ A,
                                                   const u16* __restrict__ Bm,
                                                   u16* __restrict__ q_o,
                                                   u16* __restrict__ k_o,
                                                   u16* __restrict__ v_o,
                                                   const float* __restrict__ bo,
                                                   const float* __restrict__ xres,
                                                   float* __restrict__ out){
  int b  = blockIdx.z;
  int n0 = blockIdx.x * 128, m0 = blockIdx.y * 128;
  int tid = threadIdx.x, w = tid >> 6, lane = tid & 63, lq = lane >> 4, lr = lane & 15;
  int wm = (w >> 1) * 64, wn = (w & 1) * 64;
  __shared__ u16 Al[128][40], Bl[128][40];
  f32x4 acc[4][4] = {};
  const u16* Bb = Bm + (size_t)b * 2048 * 512;

  for (int k0 = 0; k0 < 512; k0 += 32){
    #pragma unroll
    for (int rep = 0; rep < 2; ++rep){
      int task = tid + rep*256;
      int row = task >> 2, kc = task & 3;
      *(uint4*)&Al[row][kc*8] = *(const uint4*)(A  + (size_t)(m0+row)*512 + k0 + kc*8);
      *(uint4*)&Bl[row][kc*8] = *(const uint4*)(Bb + (size_t)(n0+row)*512 + k0 + kc*8);
    }
    __syncthreads();
    bf16x8 af[4], bfr[4];
    #pragma unroll
    for (int i = 0; i < 4; ++i) af[i]  = *(const bf16x8*)&Al[wm + i*16 + lr][lq*8];
    #pragma unroll
    for (int j = 0; j < 4; ++j) bfr[j] = *(const bf16x8*)&Bl[wn + j*16 + lr][lq*8];
    #pragma unroll
    for (int i = 0; i < 4; ++i)
      #pragma unroll
      for (int j = 0; j < 4; ++j)
        acc[i][j] = __builtin_amdgcn_mfma_f32_16x16x32_bf16(af[i], bfr[j], acc[i][j], 0, 0, 0);
    __syncthreads();
  }

  if (MODE == 0){
    const float QSCALE = 0.125f * 1.4426950408889634f;   // fold log2e for exp2 softmax
    #pragma unroll
    for (int i = 0; i < 4; ++i){
      int o0  = m0 + wm + i*16 + lq*4;          // 4 consecutive o, aligned
      int cls = o0 >> 9;                        // 0=q 1=k 2=v
      int hh  = (o0 >> 6) & 7;
      int d0  = o0 & 63;
      #pragma unroll
      for (int j = 0; j < 4; ++j){
        int l = n0 + wn + j*16 + lr;
        f32x4 v = acc[i][j];
        if (cls == 0){
          ushort4 s;
          s.x = f2bf(v[0]*QSCALE); s.y = f2bf(v[1]*QSCALE);
          s.z = f2bf(v[2]*QSCALE); s.w = f2bf(v[3]*QSCALE);
          *(ushort4*)(q_o + (((size_t)(b*8+hh))*2048 + l)*64 + d0) = s;
        } else if (cls == 1){
          ushort4 s;
          s.x = f2bf(v[0]); s.y = f2bf(v[1]); s.z = f2bf(v[2]); s.w = f2bf(v[3]);
          *(ushort4*)(k_o + (((size_t)(b*8+hh))*2048 + l)*64 + d0) = s;
        } else {
          #pragma unroll
          for (int r = 0; r < 4; ++r)
            v_o[(((size_t)(b*8+hh))*64 + d0 + r)*2048 + l] = f2bf(v[r]);
        }
      }
    }
  } else {
    #pragma unroll
    for (int i = 0; i < 4; ++i){
      int o0 = m0 + wm + i*16 + lq*4;
      #pragma unroll
      for (int j = 0; j < 4; ++j){
        int l = n0 + wn + j*16 + lr;
        #pragma unroll
        for (int r = 0; r < 4; ++r){
          int o = o0 + r;
          size_t idx = ((size_t)b*512 + o)*2048 + l;
          out[idx] = acc[i][j][r] + bo[o] + xres[idx];
        }
      }
    }
  }
}

// ---------------- flash attention (swapped QK^T, lane-local softmax) -------
// qT,kT: [b][h][l][64] bf16 (q pre-scaled by 0.125*log2e). vv: [b][h][64][l].
// ao out: [b][l][h*64+d] bf16.
__global__ __launch_bounds__(256) void attn_kernel(const u16* __restrict__ qT,
                                                   const u16* __restrict__ kT,
                                                   const u16* __restrict__ vv,
                                                   u16* __restrict__ ao){
  // XCD-aware decode: all 32 q-blocks of a (b,h) land on the same XCD's L2.
  int flat = blockIdx.x;             // 0..1023
  int xcd = flat & 7, t = flat >> 3;
  int bh = xcd*4 + (t & 3);          // 0..31
  int qb = t >> 2;                   // 0..31
  int tid = threadIdx.x, w = tid >> 6, lane = tid & 63, lq = lane >> 4, lr = lane & 15;
  int i0 = qb*64 + w*16;
  size_t headoff = (size_t)bh * 2048 * 64;
  __shared__ u16 Kl[64][72], Vl[64][72], Pl[4][16][72];

  // Q as B-operand: col=lr <-> q-row i0+lr, contraction d = lq*8+e
  bf16x8 qf0 = *(const bf16x8*)(qT + headoff + (size_t)(i0 + lr)*64 + lq*8);
  bf16x8 qf1 = *(const bf16x8*)(qT + headoff + (size_t)(i0 + lr)*64 + 32 + lq*8);

  f32x4 of[4] = {};
  float mrow = -1e30f, lrow = 0.f;

  for (int j0 = 0; j0 < 2048; j0 += 64){
    #pragma unroll
    for (int rep = 0; rep < 2; ++rep){
      int task = tid + rep*256;
      int r = task >> 3, cc = task & 7;
      *(uint4*)&Kl[r][cc*8] = *(const uint4*)(kT + headoff + (size_t)(j0 + r)*64 + cc*8);
      *(uint4*)&Vl[r][cc*8] = *(const uint4*)(vv + headoff + (size_t)r*2048 + j0 + cc*8);
    }
    __syncthreads();

    // S^T tile: sa[jt][r] = S[q = i0+lr][k = j0 + jt*16 + lq*4 + r]
    f32x4 sa[4] = {};
    __builtin_amdgcn_s_setprio(1);
    #pragma unroll
    for (int jt = 0; jt < 4; ++jt){
      bf16x8 kf0 = *(const bf16x8*)&Kl[jt*16 + lr][lq*8];
      bf16x8 kf1 = *(const bf16x8*)&Kl[jt*16 + lr][32 + lq*8];
      sa[jt] = __builtin_amdgcn_mfma_f32_16x16x32_bf16(kf0, qf0, sa[jt], 0, 0, 0);
      sa[jt] = __builtin_amdgcn_mfma_f32_16x16x32_bf16(kf1, qf1, sa[jt], 0, 0, 0);
    }
    __builtin_amdgcn_s_setprio(0);

    // lane-local online softmax for q-row (i0+lr): 16 values + 2 shuffles
    float cm = sa[0][0];
    #pragma unroll
    for (int jt = 0; jt < 4; ++jt)
      #pragma unroll
      for (int r = 0; r < 4; ++r) cm = fmaxf(cm, sa[jt][r]);
    cm = fmaxf(cm, __shfl_xor(cm, 16));
    cm = fmaxf(cm, __shfl_xor(cm, 32));
    float nm = fmaxf(mrow, cm);
    float alpha = __builtin_amdgcn_exp2f(mrow - nm);
    mrow = nm;
    float rs = 0.f;
    #pragma unroll
    for (int jt = 0; jt < 4; ++jt)
      #pragma unroll
      for (int r = 0; r < 4; ++r){
        float p = __builtin_amdgcn_exp2f(sa[jt][r] - nm);
        sa[jt][r] = p; rs += p;
      }
    rs += __shfl_xor(rs, 16);
    rs += __shfl_xor(rs, 32);
    lrow = lrow*alpha + rs;

    // P -> per-wave LDS, packed b64 writes (P[q=lr][k])
    #pragma unroll
    for (int jt = 0; jt < 4; ++jt){
      bf16x4 pv;
      #pragma unroll
      for (int r = 0; r < 4; ++r) pv[r] = (__bf16)sa[jt][r];
      *(bf16x4*)&Pl[w][lr][jt*16 + lq*4] = pv;
    }

    // rescale O: O[q = lq*4+r][d = dt*16+lr] needs alpha of q-row lq*4+r
    float a0 = __shfl(alpha, lq*4 + 0, 16);
    float a1 = __shfl(alpha, lq*4 + 1, 16);
    float a2 = __shfl(alpha, lq*4 + 2, 16);
    float a3 = __shfl(alpha, lq*4 + 3, 16);
    #pragma unroll
    for (int dt = 0; dt < 4; ++dt){
      f32x4 o = of[dt];
      o[0] *= a0; o[1] *= a1; o[2] *= a2; o[3] *= a3;
      of[dt] = o;
    }

    __builtin_amdgcn_s_setprio(1);
    #pragma unroll
    for (int jk = 0; jk < 2; ++jk){
      bf16x8 pa = *(const bf16x8*)&Pl[w][lr][jk*32 + lq*8];
      #pragma unroll
      for (int dt = 0; dt < 4; ++dt){
        bf16x8 vb = *(const bf16x8*)&Vl[dt*16 + lr][jk*32 + lq*8];
        of[dt] = __builtin_amdgcn_mfma_f32_16x16x32_bf16(pa, vb, of[dt], 0, 0, 0);
      }
    }
    __builtin_amdgcn_s_setprio(0);
    __syncthreads();
  }

  float inv = 1.f / lrow;               // for q-row i0+lr
  float i0v = __shfl(inv, lq*4 + 0, 16);
  float i1v = __shfl(inv, lq*4 + 1, 16);
  float i2v = __shfl(inv, lq*4 + 2, 16);
  float i3v = __shfl(inv, lq*4 + 3, 16);
  int b = bh >> 3, h = bh & 7;
  #pragma unroll
  for (int dt = 0; dt < 4; ++dt){
    size_t base = ((size_t)(b*2048) + i0 + lq*4)*512 + h*64 + dt*16 + lr;
    ao[base        ] = f2bf(of[dt][0]*i0v);
    ao[base +   512] = f2bf(of[dt][1]*i1v);
    ao[base + 2*512] = f2bf(of[dt][2]*i2v);
    ao[base + 3*512] = f2bf(of[dt][3]*i3v);
  }
}

extern "C" void kernel_launch(void* const* d_in, const int* in_sizes, int n_in,
                              void* d_out, int out_size, void* d_ws, size_t ws_size,
                              hipStream_t stream) {
  const float* x    = (const float*)d_in[0];
  const float* gw   = (const float*)d_in[1];
  const float* gb   = (const float*)d_in[2];
  const float* wqkv = (const float*)d_in[3];
  const float* wout = (const float*)d_in[4];
  const float* bout = (const float*)d_in[5];
  float* out = (float*)d_out;
  char* ws = (char*)d_ws;

  // workspace layout (bytes) — total 42 MB as before
  const size_t MB8 = (size_t)4*512*2048*2;          // 8,388,608
  u16* ao  = (u16*)(ws);                            // attn output [b][l][512]
  u16* nxT = (u16*)(ws + MB8);                      // [b][l][512]
  u16* wqb = (u16*)(ws + 2*MB8);                    // 1,572,864
  u16* wob = (u16*)(ws + 2*MB8 + 1572864);          // 524,288
  u16* qT  = (u16*)(ws + 2*MB8 + 2097152);          // 3 x 8MB: qT, kT, vv
  u16* kT  = qT + (size_t)4*8*2048*64;
  u16* vv  = kT + (size_t)4*8*2048*64;
  // gn scratch: aliases qT region (dead until QKV gemm, which runs after)
  float2* pstat = (float2*)qT;                      // 512 float2
  float2* stat  = (float2*)((char*)qT + 8192);      // 128 float2

  gnstat_kernel<<<512, 256, 0, stream>>>(x, pstat);
  gnfin_kernel<<<1, 128, 0, stream>>>(pstat, stat);
  castw_kernel<<<1024, 256, 0, stream>>>(wqkv, wout, wqb, wob);
  normtrans_kernel<<<dim3(32, 8, 4), 256, 0, stream>>>(x, stat, gw, gb, nxT);
  gemm_kernel<0><<<dim3(16, 12, 4), 256, 0, stream>>>(wqb, nxT, qT, kT, vv,
                                                      nullptr, nullptr, nullptr);
  attn_kernel<<<1024, 256, 0, stream>>>(qT, kT, vv, ao);
  gemm_kernel<1><<<dim3(16, 4, 4), 256, 0, stream>>>(wob, ao, nullptr, nullptr, nullptr,
                                                     bout, x, out);
}

// Round 6
// 193.677 us; speedup vs baseline: 1.3668x; 1.0563x over previous
//
#include <hip/hip_runtime.h>

#define DEVI __device__ __forceinline__

typedef unsigned short u16;
typedef unsigned int u32;
typedef __attribute__((ext_vector_type(8))) __bf16 bf16x8;
typedef __attribute__((ext_vector_type(4))) __bf16 bf16x4;
typedef __attribute__((ext_vector_type(2))) __bf16 bf16x2;
typedef __attribute__((ext_vector_type(4))) float f32x4;
typedef __attribute__((ext_vector_type(16))) float f32x16;
typedef __attribute__((ext_vector_type(4))) u32 u32x4;

DEVI u16 f2bf(float f){
  u32 u = __float_as_uint(f);
  return (u16)((u + 0x7FFFu + ((u >> 16) & 1u)) >> 16);
}
DEVI u32 pk2(float lo, float hi){
  bf16x2 t; t[0] = (__bf16)lo; t[1] = (__bf16)hi;
  return __builtin_bit_cast(u32, t);
}

// ---------------- GN pass 1: partial sums per (group, quarter) ----------------
__global__ __launch_bounds__(256) void gnstat_kernel(const float* __restrict__ x,
                                                     float2* __restrict__ pstat){
  int bg = blockIdx.x >> 2, qt = blockIdx.x & 3;
  const float4* xin = (const float4*)(x + (size_t)bg*32768 + qt*8192);
  int tid = threadIdx.x;
  float s1 = 0.f, s2 = 0.f;
  #pragma unroll
  for (int i = 0; i < 8; ++i){
    float4 v = xin[tid + i*256];
    s1 += v.x + v.y + v.z + v.w;
    s2 += v.x*v.x + v.y*v.y + v.z*v.z + v.w*v.w;
  }
  __shared__ float red[8];
  int lane = tid & 63, w = tid >> 6;
  for (int off = 32; off; off >>= 1){
    s1 += __shfl_down(s1, off);
    s2 += __shfl_down(s2, off);
  }
  if (lane == 0){ red[w] = s1; red[4 + w] = s2; }
  __syncthreads();
  if (tid == 0){
    pstat[blockIdx.x] = make_float2(red[0]+red[1]+red[2]+red[3],
                                    red[4]+red[5]+red[6]+red[7]);
  }
}

// ---------------- GN pass 2: finalize mu/rsigma per group ----------------
__global__ __launch_bounds__(128) void gnfin_kernel(const float2* __restrict__ pstat,
                                                    float2* __restrict__ stat){
  int t = threadIdx.x;       // 128 groups total (4 b * 32 g)
  float s1 = 0.f, s2 = 0.f;
  #pragma unroll
  for (int i = 0; i < 4; ++i){
    float2 p = pstat[t*4 + i];
    s1 += p.x; s2 += p.y;
  }
  float mu = s1 * (1.f/32768.f);
  float var = s2 * (1.f/32768.f) - mu*mu;
  stat[t] = make_float2(mu, rsqrtf(var + 1e-5f));
}

// ------- normalize + transpose: x[b][c][l] fp32 -> nxT[b][l][c] bf16 -------
__global__ __launch_bounds__(256) void normtrans_kernel(const float* __restrict__ x,
                                                        const float2* __restrict__ stat,
                                                        const float* __restrict__ gw,
                                                        const float* __restrict__ gb,
                                                        u16* __restrict__ nxT){
  int b = blockIdx.z, c0 = blockIdx.y * 64, l0 = blockIdx.x * 64;
  __shared__ u16 T[64][72];
  int tid = threadIdx.x;
  #pragma unroll
  for (int rep = 0; rep < 2; ++rep){
    int task = tid + rep*256;
    int r = task >> 3, cc = task & 7;          // channel row r, l-chunk cc
    int ch = c0 + r;
    float2 st = stat[b*32 + (ch >> 4)];
    float ga = gw[ch] * st.y;
    float be = gb[ch] - st.x * ga;
    const float4* src = (const float4*)(x + ((size_t)(b*512 + ch))*2048 + l0 + cc*8);
    float4 v0 = src[0], v1 = src[1];
    ushort4 o0, o1;
    o0.x = f2bf(v0.x*ga + be); o0.y = f2bf(v0.y*ga + be);
    o0.z = f2bf(v0.z*ga + be); o0.w = f2bf(v0.w*ga + be);
    o1.x = f2bf(v1.x*ga + be); o1.y = f2bf(v1.y*ga + be);
    o1.z = f2bf(v1.z*ga + be); o1.w = f2bf(v1.w*ga + be);
    *(ushort4*)&T[r][cc*8]     = o0;
    *(ushort4*)&T[r][cc*8 + 4] = o1;
  }
  __syncthreads();
  #pragma unroll
  for (int rep = 0; rep < 2; ++rep){
    int task = tid + rep*256;
    int r = task >> 3, cc = task & 7;          // r = local l, cc = c-chunk
    u16 tmp[8];
    #pragma unroll
    for (int i = 0; i < 8; ++i) tmp[i] = T[cc*8 + i][r];
    *(uint4*)(nxT + ((size_t)(b*2048 + l0 + r))*512 + c0 + cc*8) = *(uint4*)tmp;
  }
}

// ---------------- cast weights fp32 -> bf16 ----------------
__global__ __launch_bounds__(256) void castw_kernel(const float* __restrict__ wq,
                                                    const float* __restrict__ wo,
                                                    u16* __restrict__ wqb,
                                                    u16* __restrict__ wob){
  int t = blockIdx.x * 256 + threadIdx.x;     // 262144 float4 tasks
  const int NQ4 = (1536*512)/4;               // 196608
  float4 v; u16* dst;
  if (t < NQ4){ v = ((const float4*)wq)[t]; dst = wqb + t*4; }
  else        { int u_ = t - NQ4; v = ((const float4*)wo)[u_]; dst = wob + u_*4; }
  ushort4 s;
  s.x = f2bf(v.x); s.y = f2bf(v.y); s.z = f2bf(v.z); s.w = f2bf(v.w);
  *(ushort4*)dst = s;
}

// ---------------- GEMM: C[o][l] = sum_c A[o][c] * B[l][c]^T  (bf16 MFMA) ----
// MODE 0 epilogue:
//   q -> qT [b][h][l][64] (scaled by 0.125*log2e)
//   k -> kF MFMA-A-fragment order: off = ((k>>5)*4 + (d>>4))*512
//                                        + ((d>>3)&1)*256 + (k&31)*8 + (d&7)
//   v -> vF MFMA-A-fragment order: off = ((k>>4)*2 + (d>>5))*512
//                                        + ((k>>3)&1)*256 + (d&31)*8 + (k&7)
// MODE 1: epilogue adds b_out[o] + x residual, writes fp32 d_out[b][o][l].
template<int MODE>
__global__ __launch_bounds__(256) void gemm_kernel(const u16* __restrict__ A,
                                                   const u16* __restrict__ Bm,
                                                   u16* __restrict__ q_o,
                                                   u16* __restrict__ k_o,
                                                   u16* __restrict__ v_o,
                                                   const float* __restrict__ bo,
                                                   const float* __restrict__ xres,
                                                   float* __restrict__ out){
  int b  = blockIdx.z;
  int n0 = blockIdx.x * 128, m0 = blockIdx.y * 128;
  int tid = threadIdx.x, w = tid >> 6, lane = tid & 63, lq = lane >> 4, lr = lane & 15;
  int wm = (w >> 1) * 64, wn = (w & 1) * 64;
  __shared__ u16 Al[128][40], Bl[128][40];
  f32x4 acc[4][4] = {};
  const u16* Bb = Bm + (size_t)b * 2048 * 512;

  for (int k0 = 0; k0 < 512; k0 += 32){
    #pragma unroll
    for (int rep = 0; rep < 2; ++rep){
      int task = tid + rep*256;
      int row = task >> 2, kc = task & 3;
      *(uint4*)&Al[row][kc*8] = *(const uint4*)(A  + (size_t)(m0+row)*512 + k0 + kc*8);
      *(uint4*)&Bl[row][kc*8] = *(const uint4*)(Bb + (size_t)(n0+row)*512 + k0 + kc*8);
    }
    __syncthreads();
    bf16x8 af[4], bfr[4];
    #pragma unroll
    for (int i = 0; i < 4; ++i) af[i]  = *(const bf16x8*)&Al[wm + i*16 + lr][lq*8];
    #pragma unroll
    for (int j = 0; j < 4; ++j) bfr[j] = *(const bf16x8*)&Bl[wn + j*16 + lr][lq*8];
    #pragma unroll
    for (int i = 0; i < 4; ++i)
      #pragma unroll
      for (int j = 0; j < 4; ++j)
        acc[i][j] = __builtin_amdgcn_mfma_f32_16x16x32_bf16(af[i], bfr[j], acc[i][j], 0, 0, 0);
    __syncthreads();
  }

  if (MODE == 0){
    const float QSCALE = 0.125f * 1.4426950408889634f;   // fold log2e for exp2 softmax
    #pragma unroll
    for (int i = 0; i < 4; ++i){
      int o0  = m0 + wm + i*16 + lq*4;          // 4 consecutive o, aligned
      int cls = o0 >> 9;                        // 0=q 1=k 2=v
      int hh  = (o0 >> 6) & 7;
      int d0  = o0 & 63;
      size_t hbase = (size_t)(b*8+hh) * 2048 * 64;
      #pragma unroll
      for (int j = 0; j < 4; ++j){
        int l = n0 + wn + j*16 + lr;            // column index (seq pos / k-idx)
        f32x4 v = acc[i][j];
        if (cls == 0){
          ushort4 s;
          s.x = f2bf(v[0]*QSCALE); s.y = f2bf(v[1]*QSCALE);
          s.z = f2bf(v[2]*QSCALE); s.w = f2bf(v[3]*QSCALE);
          *(ushort4*)(q_o + hbase + (size_t)l*64 + d0) = s;
        } else if (cls == 1){
          size_t off = (size_t)(((l>>5)*4 + (d0>>4)))*512
                     + ((d0>>3)&1)*256 + (l&31)*8 + (d0&7);
          ushort4 s;
          s.x = f2bf(v[0]); s.y = f2bf(v[1]); s.z = f2bf(v[2]); s.w = f2bf(v[3]);
          *(ushort4*)(k_o + hbase + off) = s;
        } else {
          size_t off = (size_t)(((l>>4)*2 + (d0>>5)))*512
                     + ((l>>3)&1)*256 + (l&7);
          #pragma unroll
          for (int r = 0; r < 4; ++r)
            v_o[hbase + off + ((d0+r)&31)*8] = f2bf(v[r]);
        }
      }
    }
  } else {
    #pragma unroll
    for (int i = 0; i < 4; ++i){
      int o0 = m0 + wm + i*16 + lq*4;
      #pragma unroll
      for (int j = 0; j < 4; ++j){
        int l = n0 + wn + j*16 + lr;
        #pragma unroll
        for (int r = 0; r < 4; ++r){
          int o = o0 + r;
          size_t idx = ((size_t)b*512 + o)*2048 + l;
          out[idx] = acc[i][j][r] + bo[o] + xres[idx];
        }
      }
    }
  }
}

// ------- flash attention: 32x32 MFMA, swapped operands, no LDS/barriers ----
// qT: [b][h][l][64] bf16 (pre-scaled by 0.125*log2e).
// kF/vF: MFMA fragment order (see gemm epilogue). ao out: [b][l][h*64+d] bf16.
// One wave = 32 q-rows; q = lane&31 is lane-local through S, softmax, and O.
__global__ __launch_bounds__(256) void attn_kernel(const u16* __restrict__ qT,
                                                   const u16* __restrict__ kF,
                                                   const u16* __restrict__ vF,
                                                   u16* __restrict__ ao){
  int flat = blockIdx.x;              // 0..511
  int xcd = flat & 7, t = flat >> 3;  // 4 heads per XCD for K/V L2 locality
  int bh = xcd*4 + (t & 3);           // 0..31
  int qb = t >> 2;                    // 0..15
  int tid = threadIdx.x, w = tid >> 6, l = tid & 63;
  int l31 = l & 31, h = l >> 5;
  int q0 = qb*128 + w*32;
  size_t hoff = (size_t)bh * 2048 * 64;

  // Q as B-operand: B[col=q=l31][kc=8h+e] = Q[q0+l31][ds*16+8h+e]
  const u16* qp = qT + hoff + (size_t)(q0 + l31)*64 + 8*h;
  bf16x8 qf0 = *(const bf16x8*)(qp);
  bf16x8 qf1 = *(const bf16x8*)(qp + 16);
  bf16x8 qf2 = *(const bf16x8*)(qp + 32);
  bf16x8 qf3 = *(const bf16x8*)(qp + 48);

  const u16* kbase = kF + hoff + (size_t)l*8;
  const u16* vbase = vF + hoff + (size_t)l*8;

  f32x16 o0 = {}, o1 = {};
  float m = -1e30f, lsum = 0.f;

  for (int tile = 0; tile < 64; ++tile){
    const u16* kt = kbase + tile*2048;
    bf16x8 kf0 = *(const bf16x8*)(kt);
    bf16x8 kf1 = *(const bf16x8*)(kt + 512);
    bf16x8 kf2 = *(const bf16x8*)(kt + 1024);
    bf16x8 kf3 = *(const bf16x8*)(kt + 1536);

    // S^T tile [k=32][q=32]: lane holds q=l31, k = (reg&3)+8*(reg>>2)+4h
    f32x16 s = {};
    s = __builtin_amdgcn_mfma_f32_32x32x16_bf16(kf0, qf0, s, 0, 0, 0);
    s = __builtin_amdgcn_mfma_f32_32x32x16_bf16(kf1, qf1, s, 0, 0, 0);
    s = __builtin_amdgcn_mfma_f32_32x32x16_bf16(kf2, qf2, s, 0, 0, 0);
    s = __builtin_amdgcn_mfma_f32_32x32x16_bf16(kf3, qf3, s, 0, 0, 0);

    // row max (lane-local 16 + pair exchange)
    float cm = s[0];
    #pragma unroll
    for (int i = 1; i < 16; ++i) cm = fmaxf(cm, s[i]);
    cm = fmaxf(cm, __shfl_xor(cm, 32));

    // defer-max (T13): only rescale when tile max exceeds running max by >8
    if (__any(cm > m + 8.f)){
      float nm = fmaxf(m, cm);
      float alpha = __builtin_amdgcn_exp2f(m - nm);
      m = nm; lsum *= alpha;
      #pragma unroll
      for (int i = 0; i < 16; ++i){ o0[i] *= alpha; o1[i] *= alpha; }
    }

    float p[16]; float rs = 0.f;
    #pragma unroll
    for (int i = 0; i < 16; ++i){
      p[i] = __builtin_amdgcn_exp2f(s[i] - m);
      rs += p[i];
    }
    rs += __shfl_xor(rs, 32);
    lsum += rs;

    // pack P pairs: a[i] = (k = 4h + pat(i)*?, consecutive k pair)
    u32 a0 = pk2(p[0],  p[1]),  a1 = pk2(p[2],  p[3]);
    u32 a2 = pk2(p[4],  p[5]),  a3 = pk2(p[6],  p[7]);
    u32 a4 = pk2(p[8],  p[9]),  a5 = pk2(p[10], p[11]);
    u32 a6 = pk2(p[12], p[13]), a7 = pk2(p[14], p[15]);
    // exchange halves: lane l <-> l^32 hold complementary k for same q
    u32 x0 = __shfl_xor((int)a0, 32), x1 = __shfl_xor((int)a1, 32);
    u32 x2 = __shfl_xor((int)a2, 32), x3 = __shfl_xor((int)a3, 32);
    u32 x4 = __shfl_xor((int)a4, 32), x5 = __shfl_xor((int)a5, 32);
    u32 x6 = __shfl_xor((int)a6, 32), x7 = __shfl_xor((int)a7, 32);
    // B-operand fragments: B[col=q][kc=8h+e], k = ks*16 + 8h + e
    u32x4 wb0, wb1;
    wb0[0] = h ? x2 : a0;  wb0[1] = h ? x3 : a1;
    wb0[2] = h ? a2 : x0;  wb0[3] = h ? a3 : x1;
    wb1[0] = h ? x6 : a4;  wb1[1] = h ? x7 : a5;
    wb1[2] = h ? a6 : x4;  wb1[3] = h ? a7 : x5;
    bf16x8 B0 = __builtin_bit_cast(bf16x8, wb0);
    bf16x8 B1 = __builtin_bit_cast(bf16x8, wb1);

    // PV: A = V fragment (row = d-local, kc = k-part)
    const u16* vt = vbase + tile*2048;
    bf16x8 vf00 = *(const bf16x8*)(vt);          // ks0, dh0
    bf16x8 vf01 = *(const bf16x8*)(vt + 512);    // ks0, dh1
    bf16x8 vf10 = *(const bf16x8*)(vt + 1024);   // ks1, dh0
    bf16x8 vf11 = *(const bf16x8*)(vt + 1536);   // ks1, dh1
    o0 = __builtin_amdgcn_mfma_f32_32x32x16_bf16(vf00, B0, o0, 0, 0, 0);
    o1 = __builtin_amdgcn_mfma_f32_32x32x16_bf16(vf01, B0, o1, 0, 0, 0);
    o0 = __builtin_amdgcn_mfma_f32_32x32x16_bf16(vf10, B1, o0, 0, 0, 0);
    o1 = __builtin_amdgcn_mfma_f32_32x32x16_bf16(vf11, B1, o1, 0, 0, 0);
  }

  // epilogue: O[q=l31][d = dh*32 + s*8 + 4h + r]
  float inv = 1.f / lsum;
  int b_ = bh >> 3, hh = bh & 7;
  size_t obase = ((size_t)(b_*2048) + q0 + l31)*512 + hh*64 + 4*h;
  #pragma unroll
  for (int s4 = 0; s4 < 4; ++s4){
    ushort4 st;
    st.x = f2bf(o0[s4*4+0]*inv); st.y = f2bf(o0[s4*4+1]*inv);
    st.z = f2bf(o0[s4*4+2]*inv); st.w = f2bf(o0[s4*4+3]*inv);
    *(ushort4*)(ao + obase + s4*8) = st;
  }
  #pragma unroll
  for (int s4 = 0; s4 < 4; ++s4){
    ushort4 st;
    st.x = f2bf(o1[s4*4+0]*inv); st.y = f2bf(o1[s4*4+1]*inv);
    st.z = f2bf(o1[s4*4+2]*inv); st.w = f2bf(o1[s4*4+3]*inv);
    *(ushort4*)(ao + obase + 32 + s4*8) = st;
  }
}

extern "C" void kernel_launch(void* const* d_in, const int* in_sizes, int n_in,
                              void* d_out, int out_size, void* d_ws, size_t ws_size,
                              hipStream_t stream) {
  const float* x    = (const float*)d_in[0];
  const float* gw   = (const float*)d_in[1];
  const float* gb   = (const float*)d_in[2];
  const float* wqkv = (const float*)d_in[3];
  const float* wout = (const float*)d_in[4];
  const float* bout = (const float*)d_in[5];
  float* out = (float*)d_out;
  char* ws = (char*)d_ws;

  // workspace layout (bytes) — total 42 MB
  const size_t MB8 = (size_t)4*512*2048*2;          // 8,388,608
  u16* ao  = (u16*)(ws);                            // attn output [b][l][512]
  u16* nxT = (u16*)(ws + MB8);                      // [b][l][512]
  u16* wqb = (u16*)(ws + 2*MB8);                    // 1,572,864
  u16* wob = (u16*)(ws + 2*MB8 + 1572864);          // 524,288
  u16* qT  = (u16*)(ws + 2*MB8 + 2097152);          // 3 x 8MB: qT, kF, vF
  u16* kF  = qT + (size_t)4*8*2048*64;
  u16* vF  = kF + (size_t)4*8*2048*64;
  // gn scratch: aliases qT region (dead until QKV gemm, which runs after)
  float2* pstat = (float2*)qT;                      // 512 float2
  float2* stat  = (float2*)((char*)qT + 8192);      // 128 float2

  gnstat_kernel<<<512, 256, 0, stream>>>(x, pstat);
  gnfin_kernel<<<1, 128, 0, stream>>>(pstat, stat);
  castw_kernel<<<1024, 256, 0, stream>>>(wqkv, wout, wqb, wob);
  normtrans_kernel<<<dim3(32, 8, 4), 256, 0, stream>>>(x, stat, gw, gb, nxT);
  gemm_kernel<0><<<dim3(16, 12, 4), 256, 0, stream>>>(wqb, nxT, qT, kF, vF,
                                                      nullptr, nullptr, nullptr);
  attn_kernel<<<512, 256, 0, stream>>>(qT, kF, vF, ao);
  gemm_kernel<1><<<dim3(16, 4, 4), 256, 0, stream>>>(wob, ao, nullptr, nullptr, nullptr,
                                                     bout, x, out);
}

// Round 7
// 177.758 us; speedup vs baseline: 1.4892x; 1.0896x over previous
//
#include <hip/hip_runtime.h>

#define DEVI __device__ __forceinline__

typedef unsigned short u16;
typedef unsigned int u32;
typedef __attribute__((ext_vector_type(8))) __bf16 bf16x8;
typedef __attribute__((ext_vector_type(2))) __bf16 bf16x2;
typedef __attribute__((ext_vector_type(4))) float f32x4;
typedef __attribute__((ext_vector_type(16))) float f32x16;
typedef __attribute__((ext_vector_type(4))) u32 u32x4;

DEVI u16 f2bf(float f){
  u32 u = __float_as_uint(f);
  return (u16)((u + 0x7FFFu + ((u >> 16) & 1u)) >> 16);
}
DEVI u32 pk2(float lo, float hi){
  bf16x2 t; t[0] = (__bf16)lo; t[1] = (__bf16)hi;
  return __builtin_bit_cast(u32, t);
}

// ---------------- GN pass 1: partial sums per (group, quarter) ----------------
__global__ __launch_bounds__(256) void gnstat_kernel(const float* __restrict__ x,
                                                     float2* __restrict__ pstat){
  int bg = blockIdx.x >> 2, qt = blockIdx.x & 3;
  const float4* xin = (const float4*)(x + (size_t)bg*32768 + qt*8192);
  int tid = threadIdx.x;
  float s1 = 0.f, s2 = 0.f;
  #pragma unroll
  for (int i = 0; i < 8; ++i){
    float4 v = xin[tid + i*256];
    s1 += v.x + v.y + v.z + v.w;
    s2 += v.x*v.x + v.y*v.y + v.z*v.z + v.w*v.w;
  }
  __shared__ float red[8];
  int lane = tid & 63, w = tid >> 6;
  for (int off = 32; off; off >>= 1){
    s1 += __shfl_down(s1, off);
    s2 += __shfl_down(s2, off);
  }
  if (lane == 0){ red[w] = s1; red[4 + w] = s2; }
  __syncthreads();
  if (tid == 0){
    pstat[blockIdx.x] = make_float2(red[0]+red[1]+red[2]+red[3],
                                    red[4]+red[5]+red[6]+red[7]);
  }
}

// ---------------- GN pass 2: finalize mu/rsigma per group ----------------
__global__ __launch_bounds__(128) void gnfin_kernel(const float2* __restrict__ pstat,
                                                    float2* __restrict__ stat){
  int t = threadIdx.x;       // 128 groups total (4 b * 32 g)
  float s1 = 0.f, s2 = 0.f;
  #pragma unroll
  for (int i = 0; i < 4; ++i){
    float2 p = pstat[t*4 + i];
    s1 += p.x; s2 += p.y;
  }
  float mu = s1 * (1.f/32768.f);
  float var = s2 * (1.f/32768.f) - mu*mu;
  stat[t] = make_float2(mu, rsqrtf(var + 1e-5f));
}

// ------- normalize + transpose: x[b][c][l] fp32 -> nxT[b][l][c] bf16 -------
__global__ __launch_bounds__(256) void normtrans_kernel(const float* __restrict__ x,
                                                        const float2* __restrict__ stat,
                                                        const float* __restrict__ gw,
                                                        const float* __restrict__ gb,
                                                        u16* __restrict__ nxT){
  int b = blockIdx.z, c0 = blockIdx.y * 64, l0 = blockIdx.x * 64;
  __shared__ u16 T[64][72];
  int tid = threadIdx.x;
  #pragma unroll
  for (int rep = 0; rep < 2; ++rep){
    int task = tid + rep*256;
    int r = task >> 3, cc = task & 7;          // channel row r, l-chunk cc
    int ch = c0 + r;
    float2 st = stat[b*32 + (ch >> 4)];
    float ga = gw[ch] * st.y;
    float be = gb[ch] - st.x * ga;
    const float4* src = (const float4*)(x + ((size_t)(b*512 + ch))*2048 + l0 + cc*8);
    float4 v0 = src[0], v1 = src[1];
    ushort4 o0, o1;
    o0.x = f2bf(v0.x*ga + be); o0.y = f2bf(v0.y*ga + be);
    o0.z = f2bf(v0.z*ga + be); o0.w = f2bf(v0.w*ga + be);
    o1.x = f2bf(v1.x*ga + be); o1.y = f2bf(v1.y*ga + be);
    o1.z = f2bf(v1.z*ga + be); o1.w = f2bf(v1.w*ga + be);
    *(ushort4*)&T[r][cc*8]     = o0;
    *(ushort4*)&T[r][cc*8 + 4] = o1;
  }
  __syncthreads();
  #pragma unroll
  for (int rep = 0; rep < 2; ++rep){
    int task = tid + rep*256;
    int r = task >> 3, cc = task & 7;          // r = local l, cc = c-chunk
    u16 tmp[8];
    #pragma unroll
    for (int i = 0; i < 8; ++i) tmp[i] = T[cc*8 + i][r];
    *(uint4*)(nxT + ((size_t)(b*2048 + l0 + r))*512 + c0 + cc*8) = *(uint4*)tmp;
  }
}

// ---------------- cast weights fp32 -> bf16 ----------------
__global__ __launch_bounds__(256) void castw_kernel(const float* __restrict__ wq,
                                                    const float* __restrict__ wo,
                                                    u16* __restrict__ wqb,
                                                    u16* __restrict__ wob){
  int t = blockIdx.x * 256 + threadIdx.x;     // 262144 float4 tasks
  const int NQ4 = (1536*512)/4;               // 196608
  float4 v; u16* dst;
  if (t < NQ4){ v = ((const float4*)wq)[t]; dst = wqb + t*4; }
  else        { int u_ = t - NQ4; v = ((const float4*)wo)[u_]; dst = wob + u_*4; }
  ushort4 s;
  s.x = f2bf(v.x); s.y = f2bf(v.y); s.z = f2bf(v.z); s.w = f2bf(v.w);
  *(ushort4*)dst = s;
}

// ---------------- GEMM: C[o][l] = sum_c A[o][c] * B[l][c]^T  (bf16 MFMA) ----
// BK=64 staged per barrier pair (half the barriers of BK=32).
// MODE 0 epilogue:
//   q -> qT [b][h][l][64] (scaled by 0.125*log2e)
//   k -> kF MFMA-A-fragment order: off = ((k>>5)*4 + (d>>4))*512
//                                        + ((d>>3)&1)*256 + (k&31)*8 + (d&7)
//   v -> vF MFMA-A-fragment order: off = ((k>>4)*2 + (d>>5))*512
//                                        + ((k>>3)&1)*256 + (d&31)*8 + (k&7)
// MODE 1: epilogue adds b_out[o] + x residual, writes fp32 d_out[b][o][l].
template<int MODE>
__global__ __launch_bounds__(256) void gemm_kernel(const u16* __restrict__ A,
                                                   const u16* __restrict__ Bm,
                                                   u16* __restrict__ q_o,
                                                   u16* __restrict__ k_o,
                                                   u16* __restrict__ v_o,
                                                   const float* __restrict__ bo,
                                                   const float* __restrict__ xres,
                                                   float* __restrict__ out){
  int b  = blockIdx.z;
  int n0 = blockIdx.x * 128, m0 = blockIdx.y * 128;
  int tid = threadIdx.x, w = tid >> 6, lane = tid & 63, lq = lane >> 4, lr = lane & 15;
  int wm = (w >> 1) * 64, wn = (w & 1) * 64;
  __shared__ u16 Al[2][128][40], Bl[2][128][40];
  f32x4 acc[4][4] = {};
  const u16* Bb = Bm + (size_t)b * 2048 * 512;

  for (int k0 = 0; k0 < 512; k0 += 64){
    #pragma unroll
    for (int rep = 0; rep < 4; ++rep){
      int task = tid + rep*256;                // 1024 tasks: 128 rows x 8 kc
      int row = task >> 3, kc = task & 7;
      *(uint4*)&Al[kc>>2][row][(kc&3)*8] = *(const uint4*)(A  + (size_t)(m0+row)*512 + k0 + kc*8);
      *(uint4*)&Bl[kc>>2][row][(kc&3)*8] = *(const uint4*)(Bb + (size_t)(n0+row)*512 + k0 + kc*8);
    }
    __syncthreads();
    #pragma unroll
    for (int half = 0; half < 2; ++half){
      bf16x8 af[4], bfr[4];
      #pragma unroll
      for (int i = 0; i < 4; ++i) af[i]  = *(const bf16x8*)&Al[half][wm + i*16 + lr][lq*8];
      #pragma unroll
      for (int j = 0; j < 4; ++j) bfr[j] = *(const bf16x8*)&Bl[half][wn + j*16 + lr][lq*8];
      #pragma unroll
      for (int i = 0; i < 4; ++i)
        #pragma unroll
        for (int j = 0; j < 4; ++j)
          acc[i][j] = __builtin_amdgcn_mfma_f32_16x16x32_bf16(af[i], bfr[j], acc[i][j], 0, 0, 0);
    }
    __syncthreads();
  }

  if (MODE == 0){
    const float QSCALE = 0.125f * 1.4426950408889634f;   // fold log2e for exp2 softmax
    #pragma unroll
    for (int i = 0; i < 4; ++i){
      int o0  = m0 + wm + i*16 + lq*4;          // 4 consecutive o, aligned
      int cls = o0 >> 9;                        // 0=q 1=k 2=v
      int hh  = (o0 >> 6) & 7;
      int d0  = o0 & 63;
      size_t hbase = (size_t)(b*8+hh) * 2048 * 64;
      #pragma unroll
      for (int j = 0; j < 4; ++j){
        int l = n0 + wn + j*16 + lr;            // column index (seq pos / k-idx)
        f32x4 v = acc[i][j];
        if (cls == 0){
          ushort4 s;
          s.x = f2bf(v[0]*QSCALE); s.y = f2bf(v[1]*QSCALE);
          s.z = f2bf(v[2]*QSCALE); s.w = f2bf(v[3]*QSCALE);
          *(ushort4*)(q_o + hbase + (size_t)l*64 + d0) = s;
        } else if (cls == 1){
          size_t off = (size_t)(((l>>5)*4 + (d0>>4)))*512
                     + ((d0>>3)&1)*256 + (l&31)*8 + (d0&7);
          ushort4 s;
          s.x = f2bf(v[0]); s.y = f2bf(v[1]); s.z = f2bf(v[2]); s.w = f2bf(v[3]);
          *(ushort4*)(k_o + hbase + off) = s;
        } else {
          size_t off = (size_t)(((l>>4)*2 + (d0>>5)))*512
                     + ((l>>3)&1)*256 + (l&7);
          #pragma unroll
          for (int r = 0; r < 4; ++r)
            v_o[hbase + off + ((d0+r)&31)*8] = f2bf(v[r]);
        }
      }
    }
  } else {
    #pragma unroll
    for (int i = 0; i < 4; ++i){
      int o0 = m0 + wm + i*16 + lq*4;
      #pragma unroll
      for (int j = 0; j < 4; ++j){
        int l = n0 + wn + j*16 + lr;
        #pragma unroll
        for (int r = 0; r < 4; ++r){
          int o = o0 + r;
          size_t idx = ((size_t)b*512 + o)*2048 + l;
          out[idx] = acc[i][j][r] + bo[o] + xres[idx];
        }
      }
    }
  }
}

// ------- flash attention: 32x32 MFMA, no LDS, software-pipelined ----------
// qT: [b][h][l][64] bf16 (pre-scaled by 0.125*log2e).
// kF/vF: MFMA fragment order (see gemm epilogue). ao out: [b][l][h*64+d] bf16.
// Pipeline: QK^T(t+1) issued before softmax(t) (matrix pipe under VALU);
// K/V fragment loads prefetched one stage ahead (hides L2 latency).
__global__ __launch_bounds__(256, 2) void attn_kernel(const u16* __restrict__ qT,
                                                      const u16* __restrict__ kF,
                                                      const u16* __restrict__ vF,
                                                      u16* __restrict__ ao){
  int flat = blockIdx.x;              // 0..511
  int xcd = flat & 7, tt = flat >> 3; // 4 heads per XCD for K/V L2 locality
  int bh = xcd*4 + (tt & 3);          // 0..31
  int qb = tt >> 2;                   // 0..15
  int tid = threadIdx.x, w = tid >> 6, l = tid & 63;
  int l31 = l & 31, h = l >> 5;
  int q0 = qb*128 + w*32;
  size_t hoff = (size_t)bh * 2048 * 64;

  // Q as B-operand: B[col=q=l31][kc=8h+e] = Q[q0+l31][ds*16+8h+e]
  const u16* qp = qT + hoff + (size_t)(q0 + l31)*64 + 8*h;
  bf16x8 qf0 = *(const bf16x8*)(qp);
  bf16x8 qf1 = *(const bf16x8*)(qp + 16);
  bf16x8 qf2 = *(const bf16x8*)(qp + 32);
  bf16x8 qf3 = *(const bf16x8*)(qp + 48);

  const u16* kbase = kF + hoff + (size_t)l*8;
  const u16* vbase = vF + hoff + (size_t)l*8;

  f32x16 o0 = {}, o1 = {};
  float m = -1e30f, lsum = 0.f;

  bf16x8 kA0,kA1,kA2,kA3, kB0,kB1,kB2,kB3;
  bf16x8 vA0,vA1,vA2,vA3, vB0,vB1,vB2,vB3;
  f32x16 sA, sB;
  bf16x8 Bf0, Bf1;

#define LDK(P, t) { const u16* kt_ = kbase + (t)*2048;                         \
    P##0 = *(const bf16x8*)(kt_);        P##1 = *(const bf16x8*)(kt_ + 512);   \
    P##2 = *(const bf16x8*)(kt_ + 1024); P##3 = *(const bf16x8*)(kt_ + 1536); }
#define LDV(P, t) { const u16* vt_ = vbase + (t)*2048;                         \
    P##0 = *(const bf16x8*)(vt_);        P##1 = *(const bf16x8*)(vt_ + 512);   \
    P##2 = *(const bf16x8*)(vt_ + 1024); P##3 = *(const bf16x8*)(vt_ + 1536); }
#define QKT(S, P) {                                                            \
    S = (f32x16){};                                                            \
    __builtin_amdgcn_s_setprio(1);                                             \
    S = __builtin_amdgcn_mfma_f32_32x32x16_bf16(P##0, qf0, S, 0, 0, 0);        \
    S = __builtin_amdgcn_mfma_f32_32x32x16_bf16(P##1, qf1, S, 0, 0, 0);        \
    S = __builtin_amdgcn_mfma_f32_32x32x16_bf16(P##2, qf2, S, 0, 0, 0);        \
    S = __builtin_amdgcn_mfma_f32_32x32x16_bf16(P##3, qf3, S, 0, 0, 0);        \
    __builtin_amdgcn_s_setprio(0); }
#define SMAX(S) { \
    float c0 = fmaxf(S[0],S[1]),  c1 = fmaxf(S[2],S[3]);                       \
    float c2 = fmaxf(S[4],S[5]),  c3 = fmaxf(S[6],S[7]);                       \
    float c4 = fmaxf(S[8],S[9]),  c5 = fmaxf(S[10],S[11]);                     \
    float c6 = fmaxf(S[12],S[13]),c7 = fmaxf(S[14],S[15]);                     \
    c0 = fmaxf(c0,c1); c2 = fmaxf(c2,c3); c4 = fmaxf(c4,c5); c6 = fmaxf(c6,c7);\
    c0 = fmaxf(c0,c2); c4 = fmaxf(c4,c6); c0 = fmaxf(c0,c4);                   \
    c0 = fmaxf(c0, __shfl_xor(c0, 32));                                        \
    if (__any(c0 > m + 8.f)){                                                  \
      float nm = fmaxf(m, c0);                                                 \
      float alpha = __builtin_amdgcn_exp2f(m - nm);                            \
      m = nm; lsum *= alpha;                                                   \
      _Pragma("unroll")                                                        \
      for (int i = 0; i < 16; ++i){ o0[i] *= alpha; o1[i] *= alpha; }          \
    }                                                                          \
    float p[16];                                                               \
    _Pragma("unroll")                                                          \
    for (int i = 0; i < 16; ++i) p[i] = __builtin_amdgcn_exp2f(S[i] - m);      \
    float t0 = p[0]+p[1],  t1 = p[2]+p[3],  t2 = p[4]+p[5],  t3 = p[6]+p[7];   \
    float t4 = p[8]+p[9],  t5 = p[10]+p[11],t6 = p[12]+p[13],t7 = p[14]+p[15]; \
    t0 += t1; t2 += t3; t4 += t5; t6 += t7; t0 += t2; t4 += t6; t0 += t4;      \
    lsum += t0 + __shfl_xor(t0, 32);                                           \
    u32 a0 = pk2(p[0],p[1]),   a1 = pk2(p[2],p[3]);                            \
    u32 a2 = pk2(p[4],p[5]),   a3 = pk2(p[6],p[7]);                            \
    u32 a4 = pk2(p[8],p[9]),   a5 = pk2(p[10],p[11]);                          \
    u32 a6 = pk2(p[12],p[13]), a7 = pk2(p[14],p[15]);                          \
    u32 x0 = __shfl_xor((int)a0,32), x1 = __shfl_xor((int)a1,32);              \
    u32 x2 = __shfl_xor((int)a2,32), x3 = __shfl_xor((int)a3,32);              \
    u32 x4 = __shfl_xor((int)a4,32), x5 = __shfl_xor((int)a5,32);              \
    u32 x6 = __shfl_xor((int)a6,32), x7 = __shfl_xor((int)a7,32);              \
    u32x4 wb0, wb1;                                                            \
    wb0[0] = h ? x2 : a0;  wb0[1] = h ? x3 : a1;                               \
    wb0[2] = h ? a2 : x0;  wb0[3] = h ? a3 : x1;                               \
    wb1[0] = h ? x6 : a4;  wb1[1] = h ? x7 : a5;                               \
    wb1[2] = h ? a6 : x4;  wb1[3] = h ? a7 : x5;                               \
    Bf0 = __builtin_bit_cast(bf16x8, wb0);                                     \
    Bf1 = __builtin_bit_cast(bf16x8, wb1); }
#define PVA(P) {                                                               \
    __builtin_amdgcn_s_setprio(1);                                             \
    o0 = __builtin_amdgcn_mfma_f32_32x32x16_bf16(P##0, Bf0, o0, 0, 0, 0);      \
    o1 = __builtin_amdgcn_mfma_f32_32x32x16_bf16(P##1, Bf0, o1, 0, 0, 0);      \
    o0 = __builtin_amdgcn_mfma_f32_32x32x16_bf16(P##2, Bf1, o0, 0, 0, 0);      \
    o1 = __builtin_amdgcn_mfma_f32_32x32x16_bf16(P##3, Bf1, o1, 0, 0, 0);      \
    __builtin_amdgcn_s_setprio(0); }

  // prologue: tile0 scores ready; K1/V0/V1 in flight
  LDK(kA, 0);
  QKT(sA, kA);
  LDK(kB, 1);
  LDV(vA, 0);
  LDV(vB, 1);

  for (int t = 0; t < 64; t += 2){
    int t2 = (t+2 < 64) ? t+2 : 63;
    int t3 = (t+3 < 64) ? t+3 : 63;
    // stage 1: process tile t (sA), score tile t+1, prefetch t+2
    QKT(sB, kB);
    LDK(kA, t2);
    SMAX(sA);
    PVA(vA);
    LDV(vA, t2);
    // stage 2: process tile t+1 (sB), score tile t+2, prefetch t+3
    QKT(sA, kA);
    LDK(kB, t3);
    SMAX(sB);
    PVA(vB);
    LDV(vB, t3);
  }

#undef LDK
#undef LDV
#undef QKT
#undef SMAX
#undef PVA

  // epilogue: O[q=l31][d = dh*32 + s4*8 + 4h + r]
  float inv = 1.f / lsum;
  int b_ = bh >> 3, hh = bh & 7;
  size_t obase = ((size_t)(b_*2048) + q0 + l31)*512 + hh*64 + 4*h;
  #pragma unroll
  for (int s4 = 0; s4 < 4; ++s4){
    ushort4 st;
    st.x = f2bf(o0[s4*4+0]*inv); st.y = f2bf(o0[s4*4+1]*inv);
    st.z = f2bf(o0[s4*4+2]*inv); st.w = f2bf(o0[s4*4+3]*inv);
    *(ushort4*)(ao + obase + s4*8) = st;
  }
  #pragma unroll
  for (int s4 = 0; s4 < 4; ++s4){
    ushort4 st;
    st.x = f2bf(o1[s4*4+0]*inv); st.y = f2bf(o1[s4*4+1]*inv);
    st.z = f2bf(o1[s4*4+2]*inv); st.w = f2bf(o1[s4*4+3]*inv);
    *(ushort4*)(ao + obase + 32 + s4*8) = st;
  }
}

extern "C" void kernel_launch(void* const* d_in, const int* in_sizes, int n_in,
                              void* d_out, int out_size, void* d_ws, size_t ws_size,
                              hipStream_t stream) {
  const float* x    = (const float*)d_in[0];
  const float* gw   = (const float*)d_in[1];
  const float* gb   = (const float*)d_in[2];
  const float* wqkv = (const float*)d_in[3];
  const float* wout = (const float*)d_in[4];
  const float* bout = (const float*)d_in[5];
  float* out = (float*)d_out;
  char* ws = (char*)d_ws;

  // workspace layout (bytes) — total 42 MB
  const size_t MB8 = (size_t)4*512*2048*2;          // 8,388,608
  u16* ao  = (u16*)(ws);                            // attn output [b][l][512]
  u16* nxT = (u16*)(ws + MB8);                      // [b][l][512]
  u16* wqb = (u16*)(ws + 2*MB8);                    // 1,572,864
  u16* wob = (u16*)(ws + 2*MB8 + 1572864);          // 524,288
  u16* qT  = (u16*)(ws + 2*MB8 + 2097152);          // 3 x 8MB: qT, kF, vF
  u16* kF  = qT + (size_t)4*8*2048*64;
  u16* vF  = kF + (size_t)4*8*2048*64;
  // gn scratch: aliases qT region (dead until QKV gemm, which runs after)
  float2* pstat = (float2*)qT;                      // 512 float2
  float2* stat  = (float2*)((char*)qT + 8192);      // 128 float2

  gnstat_kernel<<<512, 256, 0, stream>>>(x, pstat);
  gnfin_kernel<<<1, 128, 0, stream>>>(pstat, stat);
  castw_kernel<<<1024, 256, 0, stream>>>(wqkv, wout, wqb, wob);
  normtrans_kernel<<<dim3(32, 8, 4), 256, 0, stream>>>(x, stat, gw, gb, nxT);
  gemm_kernel<0><<<dim3(16, 12, 4), 256, 0, stream>>>(wqb, nxT, qT, kF, vF,
                                                      nullptr, nullptr, nullptr);
  attn_kernel<<<512, 256, 0, stream>>>(qT, kF, vF, ao);
  gemm_kernel<1><<<dim3(16, 4, 4), 256, 0, stream>>>(wob, ao, nullptr, nullptr, nullptr,
                                                     bout, x, out);
}